// Round 2
// baseline (2340.885 us; speedup 1.0000x reference)
//
#include <hip/hip_runtime.h>

#define BB 2
#define DD 1024
#define CC 256
#define TT 32
#define HH 8
#define FF 32
#define EE 1024
#define SCALE 0.17677669529663687f

static __device__ __forceinline__ float u2f(unsigned short u) {
  return __uint_as_float(((unsigned int)u) << 16);
}
static __device__ __forceinline__ unsigned short f2u(float f) {
  unsigned int x = __float_as_uint(f);
  x += 0x7fffu + ((x >> 16) & 1u);   // round-to-nearest-even
  return (unsigned short)(x >> 16);
}

// ---------------------------------------------------------------------------
// K0: transpose qkv_w [768][256] -> qwT [256][768], proj_w -> pwT [256][256]
__global__ void k_prep(const float* __restrict__ qw,
                       const float* __restrict__ pw,
                       float* __restrict__ qwT, float* __restrict__ pwT) {
  int i = blockIdx.x * 256 + threadIdx.x;          // 0 .. 768*256-1
  int r = i >> 8, c = i & 255;
  qwT[(size_t)c * 768 + r] = qw[i];
  if (i < 256 * 256) {
    pwT[(size_t)c * 256 + r] = pw[i];
  }
}

// ---------------------------------------------------------------------------
// K1: tp[n][b][t][c] = temb[b,t,:] . tw[n][c][:] + tb[n][c]
__global__ void k_tembproj(const float* __restrict__ temb,
                           const float* __restrict__ tw,
                           const float* __restrict__ tb,
                           float* __restrict__ tp) {
  int id = blockIdx.x;            // n*B*T + b*T + t,  192 blocks
  int t = id & (TT - 1);
  int b = (id >> 5) & (BB - 1);
  int n = id >> 6;
  __shared__ float st[EE];
  for (int e = threadIdx.x; e < EE; e += 256)
    st[e] = temb[((size_t)b * TT + t) * EE + e];
  __syncthreads();
  int c = threadIdx.x;
  const float* w = tw + ((size_t)n * CC + c) * EE;
  float acc = 0.f;
  for (int e = 0; e < EE; e += 4) {
    float4 wv = *(const float4*)(w + e);
    acc += st[e + 0] * wv.x;
    acc += st[e + 1] * wv.y;
    acc += st[e + 2] * wv.z;
    acc += st[e + 3] * wv.w;
  }
  tp[((size_t)(n * BB + b) * TT + t) * CC + c] = acc + tb[n * CC + c];
}

// ---------------------------------------------------------------------------
// K2: R[n][b][t][s][c] = silu(tp[n,b,t,:] + dist_embs(b,t,s)@dw[n].T + db[n]) @ ow[n].T + ob[n]
__global__ void k_rpe(const float* __restrict__ tp,
                      const float* __restrict__ dw,
                      const float* __restrict__ db,
                      const float* __restrict__ ow,
                      const float* __restrict__ ob,
                      const int* __restrict__ fidx,
                      float* __restrict__ R) {
  int id = blockIdx.x;            // n*B*T + b*T + t,  192 blocks
  int t = id & (TT - 1);
  int b = (id >> 5) & (BB - 1);
  int n = id >> 6;
  int c = threadIdx.x;
  __shared__ float semb[CC];
  __shared__ int sfi[TT];
  if (threadIdx.x < TT) sfi[threadIdx.x] = fidx[b * TT + threadIdx.x];
  float base = tp[((size_t)(n * BB + b) * TT + t) * CC + c];
  float dw0 = dw[(n * CC + c) * 3 + 0];
  float dw1 = dw[(n * CC + c) * 3 + 1];
  float dw2 = dw[(n * CC + c) * 3 + 2];
  float dbv = db[n * CC + c];
  float obv = ob[n * CC + c];
  const float* wrow = ow + ((size_t)n * CC + c) * CC;
  __syncthreads();
  int ft = sfi[t];
  for (int s = 0; s < TT; ++s) {
    int pd = ft - sfi[s];
    float d0 = log1pf((float)(pd > 0 ? pd : 0));
    float d1 = log1pf((float)(pd < 0 ? -pd : 0));
    float d2 = (pd == 0) ? 1.f : 0.f;
    float e = base + d0 * dw0 + d1 * dw1 + d2 * dw2 + dbv;
    float se = e / (1.f + expf(-e));   // silu
    __syncthreads();
    semb[c] = se;
    __syncthreads();
    float acc = obv;
    for (int ci = 0; ci < CC; ci += 4) {
      float4 wv = *(const float4*)(wrow + ci);
      acc += semb[ci + 0] * wv.x;
      acc += semb[ci + 1] * wv.y;
      acc += semb[ci + 2] * wv.z;
      acc += semb[ci + 3] * wv.w;
    }
    R[(((size_t)(n * BB + b) * TT + t) * TT + s) * CC + c] = acc;
  }
}

// ---------------------------------------------------------------------------
// K3: per (b,d): groupnorm -> qkv -> attn(+RPE) -> softmax -> out(+RPE) -> proj -> residual
__global__ __launch_bounds__(256, 2) void k_main(
    const float* __restrict__ x,
    const float* __restrict__ nsc,
    const float* __restrict__ nbi,
    const float* __restrict__ qwT,
    const float* __restrict__ qkb,
    const float* __restrict__ pwT,
    const float* __restrict__ pb,
    const float* __restrict__ R,
    float* __restrict__ out) {
  const int d = blockIdx.x, b = blockIdx.y;
  const int tid = threadIdx.x;
  __shared__ unsigned short xt[TT][264];   // normalized x, transposed [t][c], bf16 bits
  __shared__ float qk[3][TT][36];          // q(scaled), k, v for current head
  __shared__ float at[TT][33];             // attn (post-softmax)
  __shared__ unsigned short obuf[TT][264]; // attention output [t][c], bf16 bits
  const size_t xbase = ((size_t)(b * DD + d)) * (CC * TT);

  // ---- load x[b,d,:,:] transposed into xt[t][c]
  {
    const int c0 = tid >> 3, tq = tid & 7;
    for (int c = c0; c < CC; c += 32) {
      float4 v = *(const float4*)(x + xbase + (size_t)c * TT + tq * 4);
      xt[tq * 4 + 0][c] = f2u(v.x);
      xt[tq * 4 + 1][c] = f2u(v.y);
      xt[tq * 4 + 2][c] = f2u(v.z);
      xt[tq * 4 + 3][c] = f2u(v.w);
    }
  }
  __syncthreads();

  // ---- groupnorm: one thread per channel; groups = 8 consecutive channels x 32 t
  {
    const int c = tid;
    float s = 0.f, s2 = 0.f;
    for (int t = 0; t < TT; ++t) { float v = u2f(xt[t][c]); s += v; s2 += v * v; }
    s += __shfl_xor(s, 1); s2 += __shfl_xor(s2, 1);
    s += __shfl_xor(s, 2); s2 += __shfl_xor(s2, 2);
    s += __shfl_xor(s, 4); s2 += __shfl_xor(s2, 4);
    const float mean = s * (1.f / 256.f);
    const float var = s2 * (1.f / 256.f) - mean * mean;
    const float rs = rsqrtf(var + 1e-5f);
    const float scv = nsc[c] * rs;
    const float biv = nbi[c] - mean * scv;
    for (int t = 0; t < TT; ++t) xt[t][c] = f2u(u2f(xt[t][c]) * scv + biv);
  }
  __syncthreads();

  for (int h = 0; h < HH; ++h) {
    // ---- qkv for head h: thread = (f = tid&31, tg = tid>>5 -> 4 t's)
    {
      const int f = tid & 31, tg = tid >> 5;
      const int t0 = tg * 4;
      float a00 = 0, a01 = 0, a02 = 0, a03 = 0;
      float a10 = 0, a11 = 0, a12 = 0, a13 = 0;
      float a20 = 0, a21 = 0, a22 = 0, a23 = 0;
      const float* wp = qwT + h * 32 + f;
      for (int c = 0; c < CC; ++c) {
        const float x0 = u2f(xt[t0 + 0][c]);
        const float x1 = u2f(xt[t0 + 1][c]);
        const float x2 = u2f(xt[t0 + 2][c]);
        const float x3 = u2f(xt[t0 + 3][c]);
        const float wq = wp[(size_t)c * 768];
        const float wk = wp[(size_t)c * 768 + 256];
        const float wv = wp[(size_t)c * 768 + 512];
        a00 += wq * x0; a01 += wq * x1; a02 += wq * x2; a03 += wq * x3;
        a10 += wk * x0; a11 += wk * x1; a12 += wk * x2; a13 += wk * x3;
        a20 += wv * x0; a21 += wv * x1; a22 += wv * x2; a23 += wv * x3;
      }
      const float bq = qkb[h * 32 + f];
      const float bk = qkb[256 + h * 32 + f];
      const float bv = qkb[512 + h * 32 + f];
      qk[0][t0 + 0][f] = (a00 + bq) * SCALE;
      qk[0][t0 + 1][f] = (a01 + bq) * SCALE;
      qk[0][t0 + 2][f] = (a02 + bq) * SCALE;
      qk[0][t0 + 3][f] = (a03 + bq) * SCALE;
      qk[1][t0 + 0][f] = a10 + bk;
      qk[1][t0 + 1][f] = a11 + bk;
      qk[1][t0 + 2][f] = a12 + bk;
      qk[1][t0 + 3][f] = a13 + bk;
      qk[2][t0 + 0][f] = a20 + bv;
      qk[2][t0 + 1][f] = a21 + bv;
      qk[2][t0 + 2][f] = a22 + bv;
      qk[2][t0 + 3][f] = a23 + bv;
    }
    __syncthreads();

    // ---- attn logits + softmax: thread = (t = tid>>3, j = tid&7), s = j+8m
    {
      const int t = tid >> 3, j = tid & 7;
      const float* Rq = R + ((size_t)b * TT * TT + t) * CC + h * 32;            // + s*T*C
      const float* Rk = R + (((size_t)(BB + b) * TT + t) * TT) * CC + h * 32;   // + s*C
      float a[4];
      for (int m = 0; m < 4; ++m) {
        const int s = j + 8 * m;
        const float4* rk4 = (const float4*)(Rk + (size_t)s * CC);
        const float4* rq4 = (const float4*)(Rq + (size_t)s * (TT * CC));
        float aq = 0.f, ak = 0.f;
        for (int f4 = 0; f4 < 8; ++f4) {
          const float4 rk = rk4[f4];
          const float4 rq = rq4[f4];
          const int f = f4 * 4;
          aq += qk[0][t][f + 0] * (qk[1][s][f + 0] + rk.x);
          aq += qk[0][t][f + 1] * (qk[1][s][f + 1] + rk.y);
          aq += qk[0][t][f + 2] * (qk[1][s][f + 2] + rk.z);
          aq += qk[0][t][f + 3] * (qk[1][s][f + 3] + rk.w);
          ak += qk[1][s][f + 0] * rq.x + qk[1][s][f + 1] * rq.y +
                qk[1][s][f + 2] * rq.z + qk[1][s][f + 3] * rq.w;
        }
        a[m] = aq + SCALE * ak;
      }
      float mx = fmaxf(fmaxf(a[0], a[1]), fmaxf(a[2], a[3]));
      mx = fmaxf(mx, __shfl_xor(mx, 1));
      mx = fmaxf(mx, __shfl_xor(mx, 2));
      mx = fmaxf(mx, __shfl_xor(mx, 4));
      float e0 = expf(a[0] - mx), e1 = expf(a[1] - mx);
      float e2 = expf(a[2] - mx), e3 = expf(a[3] - mx);
      float sum = e0 + e1 + e2 + e3;
      sum += __shfl_xor(sum, 1);
      sum += __shfl_xor(sum, 2);
      sum += __shfl_xor(sum, 4);
      const float inv = 1.f / sum;
      at[t][j] = e0 * inv;
      at[t][j + 8] = e1 * inv;
      at[t][j + 16] = e2 * inv;
      at[t][j + 24] = e3 * inv;
    }
    // (no barrier needed: attn row t written & read by the same 8-lane group of one wave)

    // ---- out = attn @ (v + R_v): thread = (t, j), f = j*4..j*4+3
    {
      const int t = tid >> 3, j = tid & 7;
      const float* Rv = R + (((size_t)(2 * BB + b) * TT + t) * TT) * CC + h * 32 + j * 4;
      float o0 = 0, o1 = 0, o2 = 0, o3 = 0;
      for (int s = 0; s < TT; ++s) {
        const float av = at[t][s];
        const float4 rv = *(const float4*)(Rv + (size_t)s * CC);
        const float4 vv = *(const float4*)(&qk[2][s][j * 4]);
        o0 += av * (vv.x + rv.x);
        o1 += av * (vv.y + rv.y);
        o2 += av * (vv.z + rv.z);
        o3 += av * (vv.w + rv.w);
      }
      ushort4 pk;
      pk.x = f2u(o0); pk.y = f2u(o1); pk.z = f2u(o2); pk.w = f2u(o3);
      *(ushort4*)(&obuf[t][h * 32 + j * 4]) = pk;
    }
    __syncthreads();
  }

  // ---- proj + residual + transpose store: thread = output channel co
  {
    const int co = tid;
    float acc[TT];
#pragma unroll
    for (int t = 0; t < TT; ++t) acc[t] = 0.f;
    for (int ci = 0; ci < CC; ++ci) {
      const float w = pwT[(size_t)ci * CC + co];
#pragma unroll
      for (int t = 0; t < TT; ++t) acc[t] += w * u2f(obuf[t][ci]);
    }
    const float pbv = pb[co];
    float* dst = out + xbase + (size_t)co * TT;
#pragma unroll
    for (int tq = 0; tq < 8; ++tq) {
      float4 pk;
      pk.x = u2f(xt[tq * 4 + 0][co]) + acc[tq * 4 + 0] + pbv;
      pk.y = u2f(xt[tq * 4 + 1][co]) + acc[tq * 4 + 1] + pbv;
      pk.z = u2f(xt[tq * 4 + 2][co]) + acc[tq * 4 + 2] + pbv;
      pk.w = u2f(xt[tq * 4 + 3][co]) + acc[tq * 4 + 3] + pbv;
      *(float4*)(dst + tq * 4) = pk;
    }
  }
}

// ---------------------------------------------------------------------------
extern "C" void kernel_launch(void* const* d_in, const int* in_sizes, int n_in,
                              void* d_out, int out_size, void* d_ws, size_t ws_size,
                              hipStream_t stream) {
  const float* x      = (const float*)d_in[0];
  const float* temb   = (const float*)d_in[1];
  const float* nsc    = (const float*)d_in[2];
  const float* nbi    = (const float*)d_in[3];
  const float* qkv_w  = (const float*)d_in[4];
  const float* qkv_b  = (const float*)d_in[5];
  const float* proj_w = (const float*)d_in[6];
  const float* proj_b = (const float*)d_in[7];
  const float* dw     = (const float*)d_in[8];
  const float* db     = (const float*)d_in[9];
  const float* tw     = (const float*)d_in[10];
  const float* tb     = (const float*)d_in[11];
  const float* ow     = (const float*)d_in[12];
  const float* ob     = (const float*)d_in[13];
  const int*   fidx   = (const int*)d_in[14];
  float* out = (float*)d_out;

  float* ws  = (float*)d_ws;
  float* R   = ws;                                 // 3*B*T*T*C = 1,572,864 floats
  float* tp  = R + (size_t)3 * BB * TT * TT * CC;  // 49,152 floats
  float* qwT = tp + (size_t)3 * BB * TT * CC;      // 196,608 floats
  float* pwT = qwT + (size_t)768 * 256;            // 65,536 floats

  k_prep<<<768, 256, 0, stream>>>(qkv_w, proj_w, qwT, pwT);
  k_tembproj<<<3 * BB * TT, 256, 0, stream>>>(temb, tw, tb, tp);
  k_rpe<<<3 * BB * TT, 256, 0, stream>>>(tp, dw, db, ow, ob, fidx, R);
  dim3 g(DD, BB);
  k_main<<<g, 256, 0, stream>>>(x, nsc, nbi, qwT, qkv_b, pwT, proj_b, R, out);
}

// Round 3
// 624.836 us; speedup vs baseline: 3.7464x; 3.7464x over previous
//
#include <hip/hip_runtime.h>

#define BB 2
#define DD 1024
#define CC 256
#define TT 32
#define HH 8
#define FF 32
#define EE 1024
#define SCALE 0.17677669529663687f

typedef unsigned short u16;
typedef __attribute__((ext_vector_type(8))) short s8v;    // 8 bf16 (4 VGPRs)
typedef __attribute__((ext_vector_type(4))) float f32x4;

static __device__ __forceinline__ float u2f(u16 u) {
  return __uint_as_float(((unsigned int)u) << 16);
}
static __device__ __forceinline__ u16 f2u(float f) {
  unsigned int x = __float_as_uint(f);
  x += 0x7fffu + ((x >> 16) & 1u);   // round-to-nearest-even
  return (u16)(x >> 16);
}

// ---------------------------------------------------------------------------
// K0: pack weights into MFMA-fragment order (bf16) + transpose tw -> twT (f32)
// wpk: qkv_w frags [48 ntp][8 ks][64 lane][8]  (ntp = pass*24 + sec*8 + ntl)
// ppk: proj_w frags [16 nt][8 ks][64][8]
// opk: rpe_out_w frags [3 n][16 nt][8 ks][64][8]
// twT: [3][1024 e][256 c]
__global__ void k_prep(const float* __restrict__ qw, const float* __restrict__ pw,
                       const float* __restrict__ ow, const float* __restrict__ tw,
                       u16* __restrict__ wpk, u16* __restrict__ ppk,
                       u16* __restrict__ opk, float* __restrict__ twT) {
  int id = blockIdx.x * 256 + threadIdx.x;
  if (id < 24576) {
    int lane = id & 63, ks = (id >> 6) & 7, ntp = id >> 9;
    int p = (ntp >= 24) ? 1 : 0;
    int rem = ntp - p * 24;
    int sec = rem >> 3, ntl = rem & 7;
    int nrow = sec * 256 + p * 128 + ntl * 16 + (lane & 15);
    int k = ks * 32 + (lane >> 4) * 8;
    const float* src = qw + (size_t)nrow * 256 + k;
    u16* dst = wpk + (size_t)id * 8;
#pragma unroll
    for (int e = 0; e < 8; ++e) dst[e] = f2u(src[e]);
  } else if (id < 32768) {
    int j = id - 24576;
    int lane = j & 63, ks = (j >> 6) & 7, nt = j >> 9;
    int row = nt * 16 + (lane & 15);
    int k = ks * 32 + (lane >> 4) * 8;
    const float* src = pw + (size_t)row * 256 + k;
    u16* dst = ppk + (size_t)j * 8;
#pragma unroll
    for (int e = 0; e < 8; ++e) dst[e] = f2u(src[e]);
  } else if (id < 57344) {
    int j = id - 32768;
    int lane = j & 63, ks = (j >> 6) & 7, g = j >> 9;
    int n = g >> 4, ntg = g & 15;
    int row = ntg * 16 + (lane & 15);
    int k = ks * 32 + (lane >> 4) * 8;
    const float* src = ow + ((size_t)n * 256 + row) * 256 + k;
    u16* dst = opk + (size_t)j * 8;
#pragma unroll
    for (int e = 0; e < 8; ++e) dst[e] = f2u(src[e]);
  } else {
    int j = id - 57344;                 // 0..196607
    int n = j >> 16, r = j & 65535;
    int e = r >> 6, c0 = (r & 63) * 4;
    float4 v;
    v.x = tw[((size_t)n * 256 + c0 + 0) * 1024 + e];
    v.y = tw[((size_t)n * 256 + c0 + 1) * 1024 + e];
    v.z = tw[((size_t)n * 256 + c0 + 2) * 1024 + e];
    v.w = tw[((size_t)n * 256 + c0 + 3) * 1024 + e];
    *(float4*)(twT + (size_t)n * 262144 + (size_t)e * 256 + c0) = v;
  }
}

// ---------------------------------------------------------------------------
// K1: per (n,b,t): temb-proj (coalesced twT) + dist/silu -> E bf16 [n*2048 + b*1024 + t*32 + s][256]
__global__ __launch_bounds__(256) void k_tpe(
    const float* __restrict__ temb, const float* __restrict__ twT,
    const float* __restrict__ tb, const float* __restrict__ dw,
    const float* __restrict__ db, const int* __restrict__ fidx,
    u16* __restrict__ E) {
  int bid = blockIdx.x;           // n*64 + b*32 + t
  int t = bid & 31, b = (bid >> 5) & 1, n = bid >> 6;
  __shared__ float st[EE];
  __shared__ int sfi[TT];
  for (int e = threadIdx.x; e < EE; e += 256)
    st[e] = temb[((size_t)b * TT + t) * EE + e];
  if (threadIdx.x < TT) sfi[threadIdx.x] = fidx[b * TT + threadIdx.x];
  __syncthreads();
  int c = threadIdx.x;
  const float* wp = twT + (size_t)n * 262144 + c;
  float a0 = 0.f, a1 = 0.f, a2 = 0.f, a3 = 0.f;
  for (int e = 0; e < EE; e += 4) {
    a0 += st[e + 0] * wp[(size_t)(e + 0) * 256];
    a1 += st[e + 1] * wp[(size_t)(e + 1) * 256];
    a2 += st[e + 2] * wp[(size_t)(e + 2) * 256];
    a3 += st[e + 3] * wp[(size_t)(e + 3) * 256];
  }
  float base = a0 + a1 + a2 + a3 + tb[n * 256 + c] + db[n * 256 + c];
  float dw0 = dw[(n * 256 + c) * 3 + 0];
  float dw1 = dw[(n * 256 + c) * 3 + 1];
  float dw2 = dw[(n * 256 + c) * 3 + 2];
  int ft = sfi[t];
  u16* erow = E + ((size_t)n * 2048 + b * 1024 + t * 32) * 256 + c;
  for (int s = 0; s < TT; ++s) {
    int pd = ft - sfi[s];
    float d0 = log1pf((float)(pd > 0 ? pd : 0));
    float d1 = log1pf((float)(pd < 0 ? -pd : 0));
    float d2 = (pd == 0) ? 1.f : 0.f;
    float e = base + d0 * dw0 + d1 * dw1 + d2 * dw2;
    float se = e / (1.f + expf(-e));
    erow[(size_t)s * 256] = f2u(se);
  }
}

// ---------------------------------------------------------------------------
// K2: R = E @ ow^T + ob via MFMA. rows (per n) = 2048, N=256, K=256. R bf16.
__global__ __launch_bounds__(256) void k_rgemm(
    const u16* __restrict__ E, const u16* __restrict__ opk,
    const float* __restrict__ ob, u16* __restrict__ Rb) {
  int bid = blockIdx.x;                 // 192 = 3n * 32 mblk * 2 nblk
  int n = bid >> 6, rem = bid & 63;
  int mblk = rem >> 1, nblk = rem & 1;
  int tid = threadIdx.x;
  int w = tid >> 6, lane = tid & 63;
  int l15 = lane & 15, l4 = lane >> 4;
  size_t rowbase = (size_t)n * 2048 + mblk * 64;

  f32x4 acc[2][4];
#pragma unroll
  for (int i = 0; i < 2; ++i) {
    int ntg = nblk * 8 + w * 2 + i;
    float ov = ob[n * 256 + ntg * 16 + l15];
#pragma unroll
    for (int mt = 0; mt < 4; ++mt) acc[i][mt] = (f32x4){ov, ov, ov, ov};
  }
  for (int ks = 0; ks < 8; ++ks) {
    s8v a[4];
#pragma unroll
    for (int mt = 0; mt < 4; ++mt)
      a[mt] = *(const s8v*)(E + (rowbase + mt * 16 + l15) * 256 + ks * 32 + l4 * 8);
#pragma unroll
    for (int i = 0; i < 2; ++i) {
      int ntg = nblk * 8 + w * 2 + i;
      s8v bf = *(const s8v*)(opk + (((size_t)(n * 16 + ntg) * 8 + ks) * 64 + lane) * 8);
#pragma unroll
      for (int mt = 0; mt < 4; ++mt)
        acc[i][mt] = __builtin_amdgcn_mfma_f32_16x16x32_bf16(a[mt], bf, acc[i][mt], 0, 0, 0);
    }
  }
#pragma unroll
  for (int i = 0; i < 2; ++i) {
    int col = (nblk * 8 + w * 2 + i) * 16 + l15;
#pragma unroll
    for (int mt = 0; mt < 4; ++mt)
#pragma unroll
      for (int r = 0; r < 4; ++r)
        Rb[(rowbase + mt * 16 + l4 * 4 + r) * 256 + col] = f2u(acc[i][mt][r]);
  }
}

// ---------------------------------------------------------------------------
// K3: per (b,d): GN -> qkv(MFMA) -> attn(+RPE, VALU) -> out -> proj(MFMA) -> residual
__global__ __launch_bounds__(256, 2) void k_main(
    const float* __restrict__ x,
    const float* __restrict__ nsc, const float* __restrict__ nbi,
    const u16* __restrict__ wpk, const float* __restrict__ qkb,
    const u16* __restrict__ ppk, const float* __restrict__ pb,
    const u16* __restrict__ Rb, float* __restrict__ out) {
  // XCD-aware swizzle: xcd = bid&7; XCDs 0-3 -> b=0, 4-7 -> b=1
  int bid = blockIdx.x;
  int xcd = bid & 7, jj = bid >> 3;
  int b = xcd >> 2;
  int d = (xcd & 3) * 256 + jj;
  const int tid = threadIdx.x;
  __shared__ u16 xt[TT][264];          // normalized x [t][c] bf16
  __shared__ u16 qkvs[3][TT][136];     // q(scaled),k,v for current pass (128 f-cols)
  __shared__ float at[TT][33];         // softmax'd attn
  __shared__ u16 obuf[TT][264];        // attention output [t][c] bf16
  const size_t xbase = ((size_t)(b * DD + d)) * (CC * TT);

  // ---- load x transposed
  {
    const int c0 = tid >> 3, tq = tid & 7;
    for (int c = c0; c < CC; c += 32) {
      float4 v = *(const float4*)(x + xbase + (size_t)c * TT + tq * 4);
      xt[tq * 4 + 0][c] = f2u(v.x);
      xt[tq * 4 + 1][c] = f2u(v.y);
      xt[tq * 4 + 2][c] = f2u(v.z);
      xt[tq * 4 + 3][c] = f2u(v.w);
    }
  }
  __syncthreads();

  // ---- groupnorm (8 channels x 32 t per group; 8-lane shfl reduce)
  {
    const int c = tid;
    float s = 0.f, s2 = 0.f;
    for (int t = 0; t < TT; ++t) { float v = u2f(xt[t][c]); s += v; s2 += v * v; }
    s += __shfl_xor(s, 1); s2 += __shfl_xor(s2, 1);
    s += __shfl_xor(s, 2); s2 += __shfl_xor(s2, 2);
    s += __shfl_xor(s, 4); s2 += __shfl_xor(s2, 4);
    const float mean = s * (1.f / 256.f);
    const float var = s2 * (1.f / 256.f) - mean * mean;
    const float rs = rsqrtf(var + 1e-5f);
    const float scv = nsc[c] * rs;
    const float biv = nbi[c] - mean * scv;
    for (int t = 0; t < TT; ++t) xt[t][c] = f2u(u2f(xt[t][c]) * scv + biv);
  }
  __syncthreads();

  const int w = tid >> 6, lane = tid & 63;
  const int l15 = lane & 15, l4 = lane >> 4;
  const int t = tid >> 3, j = tid & 7;

  for (int p = 0; p < 2; ++p) {
    // ---- qkv MFMA: M=32(t), N=384 (q/k/v x 128 cols of pass p), K=256
    f32x4 acc[6][2];
#pragma unroll
    for (int i = 0; i < 6; ++i) {
      acc[i][0] = (f32x4){0.f, 0.f, 0.f, 0.f};
      acc[i][1] = (f32x4){0.f, 0.f, 0.f, 0.f};
    }
    for (int ks = 0; ks < 8; ++ks) {
      s8v a0 = *(const s8v*)&xt[l15][ks * 32 + l4 * 8];
      s8v a1 = *(const s8v*)&xt[16 + l15][ks * 32 + l4 * 8];
#pragma unroll
      for (int i = 0; i < 6; ++i) {
        int ntp = p * 24 + w * 6 + i;
        s8v bf = *(const s8v*)(wpk + ((size_t)(ntp * 8 + ks) * 64 + lane) * 8);
        acc[i][0] = __builtin_amdgcn_mfma_f32_16x16x32_bf16(a0, bf, acc[i][0], 0, 0, 0);
        acc[i][1] = __builtin_amdgcn_mfma_f32_16x16x32_bf16(a1, bf, acc[i][1], 0, 0, 0);
      }
    }
    __syncthreads();   // also guarantees previous pass's heads are done with qkvs
#pragma unroll
    for (int i = 0; i < 6; ++i) {
      int ntp_l = w * 6 + i;
      int sec = ntp_l >> 3, ntl = ntp_l & 7;
      float bias = qkb[sec * 256 + p * 128 + ntl * 16 + l15];
      int fc = ntl * 16 + l15;
#pragma unroll
      for (int mt = 0; mt < 2; ++mt)
#pragma unroll
        for (int r = 0; r < 4; ++r) {
          float v = acc[i][mt][r] + bias;
          if (sec == 0) v *= SCALE;
          qkvs[sec][mt * 16 + l4 * 4 + r][fc] = f2u(v);
        }
    }
    __syncthreads();

    // ---- 4 heads of this pass
    for (int hl = 0; hl < 4; ++hl) {
      const int h = p * 4 + hl;
      const u16* Rqb = Rb + ((size_t)(b * 1024) + t) * 256 + h * 32;            // + s*8192
      const u16* Rkb = Rb + ((size_t)2048 + b * 1024 + t * 32) * 256 + h * 32;  // + s*256
      const u16* Rvb = Rb + ((size_t)4096 + b * 1024 + t * 32) * 256 + h * 32 + j * 4;

      float qreg[32];
#pragma unroll
      for (int g = 0; g < 4; ++g) {
        s8v qq = *(const s8v*)&qkvs[0][t][hl * 32 + g * 8];
#pragma unroll
        for (int e = 0; e < 8; ++e) qreg[g * 8 + e] = u2f((u16)qq[e]);
      }
      float a[4];
#pragma unroll
      for (int m = 0; m < 4; ++m) {
        const int s = j + 8 * m;
        const u16* rk = Rkb + (size_t)s * 256;
        const u16* rq = Rqb + (size_t)s * 8192;
        float aq = 0.f, ak = 0.f;
#pragma unroll
        for (int g = 0; g < 4; ++g) {
          s8v kk = *(const s8v*)&qkvs[1][s][hl * 32 + g * 8];
          s8v rk8 = *(const s8v*)(rk + g * 8);
          s8v rq8 = *(const s8v*)(rq + g * 8);
#pragma unroll
          for (int e = 0; e < 8; ++e) {
            float kf = u2f((u16)kk[e]);
            aq += qreg[g * 8 + e] * (kf + u2f((u16)rk8[e]));
            ak += kf * u2f((u16)rq8[e]);
          }
        }
        a[m] = aq + SCALE * ak;
      }
      float mx = fmaxf(fmaxf(a[0], a[1]), fmaxf(a[2], a[3]));
      mx = fmaxf(mx, __shfl_xor(mx, 1));
      mx = fmaxf(mx, __shfl_xor(mx, 2));
      mx = fmaxf(mx, __shfl_xor(mx, 4));
      float e0 = expf(a[0] - mx), e1 = expf(a[1] - mx);
      float e2 = expf(a[2] - mx), e3 = expf(a[3] - mx);
      float sum = e0 + e1 + e2 + e3;
      sum += __shfl_xor(sum, 1);
      sum += __shfl_xor(sum, 2);
      sum += __shfl_xor(sum, 4);
      const float inv = 1.f / sum;
      at[t][j] = e0 * inv;
      at[t][j + 8] = e1 * inv;
      at[t][j + 16] = e2 * inv;
      at[t][j + 24] = e3 * inv;
      // same 8-lane group writes & reads row t -> no barrier

      float o0 = 0.f, o1 = 0.f, o2 = 0.f, o3 = 0.f;
#pragma unroll 4
      for (int s = 0; s < TT; ++s) {
        const float av = at[t][s];
        ushort4 vv = *(const ushort4*)&qkvs[2][s][hl * 32 + j * 4];
        ushort4 rv = *(const ushort4*)(Rvb + (size_t)s * 256);
        o0 += av * (u2f(vv.x) + u2f(rv.x));
        o1 += av * (u2f(vv.y) + u2f(rv.y));
        o2 += av * (u2f(vv.z) + u2f(rv.z));
        o3 += av * (u2f(vv.w) + u2f(rv.w));
      }
      ushort4 pk;
      pk.x = f2u(o0); pk.y = f2u(o1); pk.z = f2u(o2); pk.w = f2u(o3);
      *(ushort4*)(&obuf[t][h * 32 + j * 4]) = pk;
    }
  }
  __syncthreads();

  // ---- proj MFMA: M=32, N=256, K=256; + bias + residual + store [c][t]
  {
    f32x4 pacc[4][2];
#pragma unroll
    for (int i = 0; i < 4; ++i) {
      pacc[i][0] = (f32x4){0.f, 0.f, 0.f, 0.f};
      pacc[i][1] = (f32x4){0.f, 0.f, 0.f, 0.f};
    }
    for (int ks = 0; ks < 8; ++ks) {
      s8v a0 = *(const s8v*)&obuf[l15][ks * 32 + l4 * 8];
      s8v a1 = *(const s8v*)&obuf[16 + l15][ks * 32 + l4 * 8];
#pragma unroll
      for (int i = 0; i < 4; ++i) {
        s8v bf = *(const s8v*)(ppk + ((size_t)((w * 4 + i) * 8 + ks) * 64 + lane) * 8);
        pacc[i][0] = __builtin_amdgcn_mfma_f32_16x16x32_bf16(a0, bf, pacc[i][0], 0, 0, 0);
        pacc[i][1] = __builtin_amdgcn_mfma_f32_16x16x32_bf16(a1, bf, pacc[i][1], 0, 0, 0);
      }
    }
#pragma unroll
    for (int i = 0; i < 4; ++i) {
      const int co = (w * 4 + i) * 16 + l15;
      const float pbv = pb[co];
#pragma unroll
      for (int mt = 0; mt < 2; ++mt) {
        const int t0 = mt * 16 + l4 * 4;
        float4 sv;
        sv.x = pacc[i][mt][0] + u2f(xt[t0 + 0][co]) + pbv;
        sv.y = pacc[i][mt][1] + u2f(xt[t0 + 1][co]) + pbv;
        sv.z = pacc[i][mt][2] + u2f(xt[t0 + 2][co]) + pbv;
        sv.w = pacc[i][mt][3] + u2f(xt[t0 + 3][co]) + pbv;
        *(float4*)(out + xbase + (size_t)co * TT + t0) = sv;
      }
    }
  }
}

// ---------------------------------------------------------------------------
extern "C" void kernel_launch(void* const* d_in, const int* in_sizes, int n_in,
                              void* d_out, int out_size, void* d_ws, size_t ws_size,
                              hipStream_t stream) {
  const float* x      = (const float*)d_in[0];
  const float* temb   = (const float*)d_in[1];
  const float* nsc    = (const float*)d_in[2];
  const float* nbi    = (const float*)d_in[3];
  const float* qkv_w  = (const float*)d_in[4];
  const float* qkv_b  = (const float*)d_in[5];
  const float* proj_w = (const float*)d_in[6];
  const float* proj_b = (const float*)d_in[7];
  const float* dw     = (const float*)d_in[8];
  const float* db     = (const float*)d_in[9];
  const float* tw     = (const float*)d_in[10];
  const float* tb     = (const float*)d_in[11];
  const float* ow     = (const float*)d_in[12];
  const float* ob     = (const float*)d_in[13];
  const int*   fidx   = (const int*)d_in[14];
  float* out = (float*)d_out;

  float* twT = (float*)d_ws;                     // 786432 f
  u16* wpk = (u16*)(twT + 786432);               // 196608 u16
  u16* ppk = wpk + 196608;                       // 65536
  u16* opk = ppk + 65536;                        // 196608
  u16* E   = opk + 196608;                       // 1572864
  u16* Rb  = E + 1572864;                        // 1572864  (total ~10.4 MB)

  k_prep<<<992, 256, 0, stream>>>(qkv_w, proj_w, ow, tw, wpk, ppk, opk, twT);
  k_tpe<<<192, 256, 0, stream>>>(temb, twT, tb, dw, db, fidx, E);
  k_rgemm<<<192, 256, 0, stream>>>(E, opk, ob, Rb);
  k_main<<<2048, 256, 0, stream>>>(x, nsc, nbi, wpk, qkv_b, ppk, proj_b, Rb, out);
}

// Round 5
// 438.638 us; speedup vs baseline: 5.3367x; 1.4245x over previous
//
#include <hip/hip_runtime.h>

#define BB 2
#define DD 1024
#define CC 256
#define TT 32
#define HH 8
#define FF 32
#define EE 1024
#define SCALE 0.17677669529663687f

typedef unsigned short u16;
typedef unsigned int u32;
typedef __attribute__((ext_vector_type(8))) short s8v;    // 8 bf16 (4 VGPRs)
typedef __attribute__((ext_vector_type(4))) float f32x4;

static __device__ __forceinline__ float u2f(u16 u) {
  return __uint_as_float(((u32)u) << 16);
}
static __device__ __forceinline__ u16 f2u(float f) {
  u32 x = __float_as_uint(f);
  x += 0x7fffu + ((x >> 16) & 1u);   // round-to-nearest-even
  return (u16)(x >> 16);
}
// d = a.lo*b.lo + a.hi*b.hi + c   (bf16 pairs, f32 accumulate)
static __device__ __forceinline__ float dot2bf(u32 a, u32 b, float c) {
  float d;
  asm("v_dot2_f32_bf16 %0, %1, %2, %3" : "=v"(d) : "v"(a), "v"(b), "v"(c));
  return d;
}

// ---------------------------------------------------------------------------
// K0: pack weights into MFMA-fragment order (bf16) + transpose tw -> twT (f32)
// wpk2: qkv_w frags [8 h][3 sec][2 nt][8 ks][64 lane][8]
// ppk : proj_w frags [16 nt][8 ks][64][8]
// opk : rpe_out_w frags [3 n][16 nt][8 ks][64][8]
// twT : [3][1024 e][256 c]
__global__ void k_prep(const float* __restrict__ qw, const float* __restrict__ pw,
                       const float* __restrict__ ow, const float* __restrict__ tw,
                       u16* __restrict__ wpk2, u16* __restrict__ ppk,
                       u16* __restrict__ opk, float* __restrict__ twT) {
  int id = blockIdx.x * 256 + threadIdx.x;
  if (id < 24576) {
    int lane = id & 63, ks = (id >> 6) & 7, tile = id >> 9;   // 0..47
    int hh = tile / 6, r = tile % 6, sec = r >> 1, nt = r & 1;
    int nrow = sec * 256 + hh * 32 + nt * 16 + (lane & 15);
    int k = ks * 32 + (lane >> 4) * 8;
    const float* src = qw + (size_t)nrow * 256 + k;
    u16* dst = wpk2 + (size_t)id * 8;
#pragma unroll
    for (int e = 0; e < 8; ++e) dst[e] = f2u(src[e]);
  } else if (id < 32768) {
    int j = id - 24576;
    int lane = j & 63, ks = (j >> 6) & 7, nt = j >> 9;
    int row = nt * 16 + (lane & 15);
    int k = ks * 32 + (lane >> 4) * 8;
    const float* src = pw + (size_t)row * 256 + k;
    u16* dst = ppk + (size_t)j * 8;
#pragma unroll
    for (int e = 0; e < 8; ++e) dst[e] = f2u(src[e]);
  } else if (id < 57344) {
    int j = id - 32768;
    int lane = j & 63, ks = (j >> 6) & 7, g = j >> 9;
    int n = g >> 4, ntg = g & 15;
    int row = ntg * 16 + (lane & 15);
    int k = ks * 32 + (lane >> 4) * 8;
    const float* src = ow + ((size_t)n * 256 + row) * 256 + k;
    u16* dst = opk + (size_t)j * 8;
#pragma unroll
    for (int e = 0; e < 8; ++e) dst[e] = f2u(src[e]);
  } else {
    int j = id - 57344;                 // 0..196607
    int n = j >> 16, r = j & 65535;
    int e = r >> 6, c0 = (r & 63) * 4;
    float4 v;
    v.x = tw[((size_t)n * 256 + c0 + 0) * 1024 + e];
    v.y = tw[((size_t)n * 256 + c0 + 1) * 1024 + e];
    v.z = tw[((size_t)n * 256 + c0 + 2) * 1024 + e];
    v.w = tw[((size_t)n * 256 + c0 + 3) * 1024 + e];
    *(float4*)(twT + (size_t)n * 262144 + (size_t)e * 256 + c0) = v;
  }
}

// ---------------------------------------------------------------------------
// K1: per (n,b,t): temb-proj + dist/silu -> E bf16 rows [n*2048+b*1024+t*32+s][256]
__global__ __launch_bounds__(256) void k_tpe(
    const float* __restrict__ temb, const float* __restrict__ twT,
    const float* __restrict__ tb, const float* __restrict__ dw,
    const float* __restrict__ db, const int* __restrict__ fidx,
    u16* __restrict__ E) {
  int bid = blockIdx.x;           // n*64 + b*32 + t
  int t = bid & 31, b = (bid >> 5) & 1, n = bid >> 6;
  __shared__ float st[EE];
  __shared__ int sfi[TT];
  for (int e = threadIdx.x; e < EE; e += 256)
    st[e] = temb[((size_t)b * TT + t) * EE + e];
  if (threadIdx.x < TT) sfi[threadIdx.x] = fidx[b * TT + threadIdx.x];
  __syncthreads();
  int c = threadIdx.x;
  const float* wp = twT + (size_t)n * 262144 + c;
  float a0 = 0.f, a1 = 0.f, a2 = 0.f, a3 = 0.f;
  for (int e = 0; e < EE; e += 4) {
    a0 += st[e + 0] * wp[(size_t)(e + 0) * 256];
    a1 += st[e + 1] * wp[(size_t)(e + 1) * 256];
    a2 += st[e + 2] * wp[(size_t)(e + 2) * 256];
    a3 += st[e + 3] * wp[(size_t)(e + 3) * 256];
  }
  float base = a0 + a1 + a2 + a3 + tb[n * 256 + c] + db[n * 256 + c];
  float dw0 = dw[(n * 256 + c) * 3 + 0];
  float dw1 = dw[(n * 256 + c) * 3 + 1];
  float dw2 = dw[(n * 256 + c) * 3 + 2];
  int ft = sfi[t];
  u16* erow = E + ((size_t)n * 2048 + b * 1024 + t * 32) * 256 + c;
  for (int s = 0; s < TT; ++s) {
    int pd = ft - sfi[s];
    float d0 = log1pf((float)(pd > 0 ? pd : 0));
    float d1 = log1pf((float)(pd < 0 ? -pd : 0));
    float d2 = (pd == 0) ? 1.f : 0.f;
    float e = base + d0 * dw0 + d1 * dw1 + d2 * dw2;
    float se = e / (1.f + expf(-e));
    erow[(size_t)s * 256] = f2u(se);
  }
}

// ---------------------------------------------------------------------------
// K2: R = E @ ow^T + ob via MFMA, stored head-major:
//  n=0 (Rq): [b][h][s*32+t][f]  (pre-swapped so k_attn reads row t*32+s)
//  n=1 (Rk): [b][h][t*32+s][f]
//  n=2 (Rv): [b][h][t][f][s]
__global__ __launch_bounds__(256) void k_rgemm(
    const u16* __restrict__ E, const u16* __restrict__ opk,
    const float* __restrict__ ob,
    u16* __restrict__ Rq, u16* __restrict__ Rk, u16* __restrict__ Rv) {
  int bid = blockIdx.x;                 // 192 = 3n * 32 mblk * 2 nblk
  int n = bid >> 6, rem = bid & 63;
  int mblk = rem >> 1, nblk = rem & 1;
  int tid = threadIdx.x;
  int w = tid >> 6, lane = tid & 63;
  int l15 = lane & 15, l4 = lane >> 4;
  size_t rowbase = (size_t)n * 2048 + mblk * 64;

  f32x4 acc[2][4];
#pragma unroll
  for (int i = 0; i < 2; ++i) {
    int ntg = nblk * 8 + w * 2 + i;
    float ov = ob[n * 256 + ntg * 16 + l15];
#pragma unroll
    for (int mt = 0; mt < 4; ++mt) acc[i][mt] = (f32x4){ov, ov, ov, ov};
  }
  for (int ks = 0; ks < 8; ++ks) {
    s8v a[4];
#pragma unroll
    for (int mt = 0; mt < 4; ++mt)
      a[mt] = *(const s8v*)(E + (rowbase + mt * 16 + l15) * 256 + ks * 32 + l4 * 8);
#pragma unroll
    for (int i = 0; i < 2; ++i) {
      int ntg = nblk * 8 + w * 2 + i;
      s8v bf = *(const s8v*)(opk + (((size_t)(n * 16 + ntg) * 8 + ks) * 64 + lane) * 8);
#pragma unroll
      for (int mt = 0; mt < 4; ++mt)
        acc[i][mt] = __builtin_amdgcn_mfma_f32_16x16x32_bf16(a[mt], bf, acc[i][mt], 0, 0, 0);
    }
  }
#pragma unroll
  for (int i = 0; i < 2; ++i) {
    int cc = (nblk * 8 + w * 2 + i) * 16 + l15;
    int hh = cc >> 5, f = cc & 31;
#pragma unroll
    for (int mt = 0; mt < 4; ++mt)
#pragma unroll
      for (int r = 0; r < 4; ++r) {
        int rloc = mblk * 64 + mt * 16 + l4 * 4 + r;  // 0..2047
        int bb2 = rloc >> 10, tt = (rloc >> 5) & 31, ss = rloc & 31;
        size_t bh = (size_t)(bb2 * 8 + hh);
        u16 val = f2u(acc[i][mt][r]);
        if (n == 0)      Rq[(bh * 1024 + ss * 32 + tt) * 32 + f] = val;
        else if (n == 1) Rk[(bh * 1024 + tt * 32 + ss) * 32 + f] = val;
        else             Rv[((bh * 32 + tt) * 32 + f) * 32 + ss] = val;
      }
  }
}

// ---------------------------------------------------------------------------
// K3: groupnorm -> xn bf16, stored in upper half of this (b,d)'s d_out slot
__global__ __launch_bounds__(256, 4) void k_gn(
    const float* __restrict__ x, const float* __restrict__ nsc,
    const float* __restrict__ nbi, u16* __restrict__ pun) {
  int bid = blockIdx.x;
  int xcd = bid & 7, jj = bid >> 3;
  int b = xcd >> 2;
  int d = (xcd & 3) * 256 + jj;
  const int tid = threadIdx.x;
  __shared__ u16 xt[TT][264];
  const size_t xbase = ((size_t)(b * DD + d)) * 8192;
  u16* xnp = pun + xbase * 2 + 8192;     // upper half of the 32KB slot
  {
    const int c0 = tid >> 3, tq = tid & 7;
    for (int c = c0; c < CC; c += 32) {
      float4 v = *(const float4*)(x + xbase + (size_t)c * TT + tq * 4);
      xt[tq * 4 + 0][c] = f2u(v.x);
      xt[tq * 4 + 1][c] = f2u(v.y);
      xt[tq * 4 + 2][c] = f2u(v.z);
      xt[tq * 4 + 3][c] = f2u(v.w);
    }
  }
  __syncthreads();
  {
    const int c = tid;
    float s = 0.f, s2 = 0.f;
    for (int t = 0; t < TT; ++t) { float v = u2f(xt[t][c]); s += v; s2 += v * v; }
    s += __shfl_xor(s, 1); s2 += __shfl_xor(s2, 1);
    s += __shfl_xor(s, 2); s2 += __shfl_xor(s2, 2);
    s += __shfl_xor(s, 4); s2 += __shfl_xor(s2, 4);
    const float mean = s * (1.f / 256.f);
    const float var = s2 * (1.f / 256.f) - mean * mean;
    const float rs = rsqrtf(var + 1e-5f);
    const float scv = nsc[c] * rs;
    const float biv = nbi[c] - mean * scv;
    for (int t = 0; t < TT; ++t) xt[t][c] = f2u(u2f(xt[t][c]) * scv + biv);
  }
  __syncthreads();
#pragma unroll
  for (int it = 0; it < 4; ++it) {       // 1024 ushort8 units = 32x256
    int u = it * 256 + tid;
    int t = u >> 5, c = (u & 31) * 8;
    *(uint4*)(xnp + (size_t)u * 8) = *(const uint4*)&xt[t][c];
  }
}

// ---------------------------------------------------------------------------
// K4: per (b,d,h): qkv head-slice MFMA -> logits/softmax/PV via v_dot2_f32_bf16
__global__ __launch_bounds__(256, 4) void k_attn(
    u16* __restrict__ pun, const u16* __restrict__ wpk2,
    const float* __restrict__ qkb,
    const u16* __restrict__ Rq, const u16* __restrict__ Rk,
    const u16* __restrict__ Rv) {
  int bid = blockIdx.x;
  int xcd = bid & 7, jj = bid >> 3;     // jj 0..2047
  int b = xcd >> 2;
  int h = jj & 7;                       // h fastest: 8 head-blocks of same (b,d) co-resident
  int d = (xcd & 3) * 256 + (jj >> 3);
  const int tid = threadIdx.x;
  __shared__ u16 xs[32][264];
  __shared__ u16 qs[32][40];
  __shared__ u16 ks_[32][40];
  __shared__ u16 vT[32][40];    // v transposed: [f][t]
  __shared__ u16 ats[32][40];   // softmax'd attn, bf16

  u16* slot = pun + ((size_t)(b * DD + d)) * 16384;   // O half, +8192 = xn half
#pragma unroll
  for (int it = 0; it < 4; ++it) {
    int u = it * 256 + tid;
    int t = u >> 5, c = (u & 31) * 8;
    *(uint4*)&xs[t][c] = *(const uint4*)(slot + 8192 + (size_t)u * 8);
  }
  __syncthreads();

  const int w = tid >> 6, lane = tid & 63;
  const int l15 = lane & 15, l4 = lane >> 4;
  if (w < 3) {
    // sec w: q(0)/k(1)/v(2); N=32 (2 nt), M=32 (2 mt), K=256
    f32x4 acc[2][2];
#pragma unroll
    for (int nt = 0; nt < 2; ++nt) {
      acc[nt][0] = (f32x4){0.f, 0.f, 0.f, 0.f};
      acc[nt][1] = (f32x4){0.f, 0.f, 0.f, 0.f};
    }
    for (int ks = 0; ks < 8; ++ks) {
      s8v a0 = *(const s8v*)&xs[l15][ks * 32 + l4 * 8];
      s8v a1 = *(const s8v*)&xs[16 + l15][ks * 32 + l4 * 8];
#pragma unroll
      for (int nt = 0; nt < 2; ++nt) {
        s8v bf = *(const s8v*)(wpk2 + ((size_t)((h * 6 + w * 2 + nt) * 8 + ks) * 64 + lane) * 8);
        acc[nt][0] = __builtin_amdgcn_mfma_f32_16x16x32_bf16(a0, bf, acc[nt][0], 0, 0, 0);
        acc[nt][1] = __builtin_amdgcn_mfma_f32_16x16x32_bf16(a1, bf, acc[nt][1], 0, 0, 0);
      }
    }
#pragma unroll
    for (int nt = 0; nt < 2; ++nt) {
      int f = nt * 16 + l15;
      float bias = qkb[w * 256 + h * 32 + f];
#pragma unroll
      for (int mt = 0; mt < 2; ++mt)
#pragma unroll
        for (int r = 0; r < 4; ++r) {
          int t = mt * 16 + l4 * 4 + r;
          float val = acc[nt][mt][r] + bias;
          if (w == 0)      qs[t][f] = f2u(val * SCALE);
          else if (w == 1) ks_[t][f] = f2u(val);
          else             vT[f][t] = f2u(val);
        }
    }
  }
  __syncthreads();

  const int t = tid >> 3, j = tid & 7;
  const size_t bh = (size_t)(b * 8 + h);

  // ---- logits: a[m] for s = j+8m
  u32 qp[16];
#pragma unroll
  for (int p = 0; p < 4; ++p) *(uint4*)&qp[p * 4] = *(const uint4*)&qs[t][p * 8];
  float a[4];
#pragma unroll 2
  for (int m = 0; m < 4; ++m) {
    const int s = j + 8 * m;
    u32 kk[16], rk[16], rq[16];
    const u16* rkp = Rk + (bh * 1024 + t * 32 + s) * 32;
    const u16* rqp = Rq + (bh * 1024 + t * 32 + s) * 32;
#pragma unroll
    for (int p = 0; p < 4; ++p) {
      *(uint4*)&kk[p * 4] = *(const uint4*)&ks_[s][p * 8];
      *(uint4*)&rk[p * 4] = *(const uint4*)(rkp + p * 8);
      *(uint4*)&rq[p * 4] = *(const uint4*)(rqp + p * 8);
    }
    float aq = 0.f, ak = 0.f;
#pragma unroll
    for (int p = 0; p < 16; ++p) {
      aq = dot2bf(qp[p], kk[p], aq);
      aq = dot2bf(qp[p], rk[p], aq);
      ak = dot2bf(kk[p], rq[p], ak);
    }
    a[m] = aq + SCALE * ak;
  }
  // ---- softmax over 32 s (8-lane groups x 4 regs)
  {
    float mx = fmaxf(fmaxf(a[0], a[1]), fmaxf(a[2], a[3]));
    mx = fmaxf(mx, __shfl_xor(mx, 1));
    mx = fmaxf(mx, __shfl_xor(mx, 2));
    mx = fmaxf(mx, __shfl_xor(mx, 4));
    float e0 = expf(a[0] - mx), e1 = expf(a[1] - mx);
    float e2 = expf(a[2] - mx), e3 = expf(a[3] - mx);
    float sum = e0 + e1 + e2 + e3;
    sum += __shfl_xor(sum, 1);
    sum += __shfl_xor(sum, 2);
    sum += __shfl_xor(sum, 4);
    const float inv = 1.f / sum;
    ats[t][j]      = f2u(e0 * inv);
    ats[t][j + 8]  = f2u(e1 * inv);
    ats[t][j + 16] = f2u(e2 * inv);
    ats[t][j + 24] = f2u(e3 * inv);
  }
  // (row t written & read by same 8-lane group -> no barrier)

  // ---- PV: o[f] = sum_s attn[t,s]*(v[s,f] + Rv[t,s,f]) ; f = j*4+i
  u32 ap[16];
#pragma unroll
  for (int p = 0; p < 4; ++p) *(uint4*)&ap[p * 4] = *(const uint4*)&ats[t][p * 8];
  float o[4];
#pragma unroll 2
  for (int i = 0; i < 4; ++i) {
    const int f = j * 4 + i;
    u32 vp[16], rv[16];
    const u16* rvp = Rv + ((bh * 32 + t) * 32 + f) * 32;
#pragma unroll
    for (int p = 0; p < 4; ++p) {
      *(uint4*)&vp[p * 4] = *(const uint4*)&vT[f][p * 8];
      *(uint4*)&rv[p * 4] = *(const uint4*)(rvp + p * 8);
    }
    float oi = 0.f;
#pragma unroll
    for (int p = 0; p < 16; ++p) {
      oi = dot2bf(ap[p], vp[p], oi);
      oi = dot2bf(ap[p], rv[p], oi);
    }
    o[i] = oi;
  }
  ushort4 pk;
  pk.x = f2u(o[0]); pk.y = f2u(o[1]); pk.z = f2u(o[2]); pk.w = f2u(o[3]);
  *(ushort4*)(slot + (size_t)t * 256 + h * 32 + j * 4) = pk;
}

// ---------------------------------------------------------------------------
// K5: per (b,d): proj MFMA + bias + residual(xn) -> out [b][d][c][t] f32
// Reads both halves of its slot into LDS (drained before barrier), then
// overwrites the full slot with the f32 result. Strictly per-slot -> safe.
__global__ __launch_bounds__(256, 4) void k_proj(
    u16* __restrict__ pun, const u16* __restrict__ ppk,
    const float* __restrict__ pb, float* __restrict__ out) {
  int bid = blockIdx.x;
  int xcd = bid & 7, jj = bid >> 3;
  int b = xcd >> 2;
  int d = (xcd & 3) * 256 + jj;
  const int tid = threadIdx.x;
  __shared__ u16 obuf[32][264];
  __shared__ u16 xs[32][264];
  const size_t nbase = ((size_t)(b * DD + d)) * 8192;
  u16* slot = pun + nbase * 2;
#pragma unroll
  for (int it = 0; it < 4; ++it) {
    int u = it * 256 + tid;
    int t = u >> 5, c = (u & 31) * 8;
    *(uint4*)&obuf[t][c] = *(const uint4*)(slot + (size_t)u * 8);
    *(uint4*)&xs[t][c]   = *(const uint4*)(slot + 8192 + (size_t)u * 8);
  }
  __syncthreads();

  const int w = tid >> 6, lane = tid & 63;
  const int l15 = lane & 15, l4 = lane >> 4;
  f32x4 pacc[4][2];
#pragma unroll
  for (int i = 0; i < 4; ++i) {
    pacc[i][0] = (f32x4){0.f, 0.f, 0.f, 0.f};
    pacc[i][1] = (f32x4){0.f, 0.f, 0.f, 0.f};
  }
  for (int ks = 0; ks < 8; ++ks) {
    s8v a0 = *(const s8v*)&obuf[l15][ks * 32 + l4 * 8];
    s8v a1 = *(const s8v*)&obuf[16 + l15][ks * 32 + l4 * 8];
#pragma unroll
    for (int i = 0; i < 4; ++i) {
      s8v bf = *(const s8v*)(ppk + ((size_t)((w * 4 + i) * 8 + ks) * 64 + lane) * 8);
      pacc[i][0] = __builtin_amdgcn_mfma_f32_16x16x32_bf16(a0, bf, pacc[i][0], 0, 0, 0);
      pacc[i][1] = __builtin_amdgcn_mfma_f32_16x16x32_bf16(a1, bf, pacc[i][1], 0, 0, 0);
    }
  }
#pragma unroll
  for (int i = 0; i < 4; ++i) {
    const int co = (w * 4 + i) * 16 + l15;
    const float pbv = pb[co];
#pragma unroll
    for (int mt = 0; mt < 2; ++mt) {
      const int t0 = mt * 16 + l4 * 4;
      float4 sv;
      sv.x = pacc[i][mt][0] + u2f(xs[t0 + 0][co]) + pbv;
      sv.y = pacc[i][mt][1] + u2f(xs[t0 + 1][co]) + pbv;
      sv.z = pacc[i][mt][2] + u2f(xs[t0 + 2][co]) + pbv;
      sv.w = pacc[i][mt][3] + u2f(xs[t0 + 3][co]) + pbv;
      *(float4*)(out + nbase + (size_t)co * TT + t0) = sv;
    }
  }
}

// ---------------------------------------------------------------------------
extern "C" void kernel_launch(void* const* d_in, const int* in_sizes, int n_in,
                              void* d_out, int out_size, void* d_ws, size_t ws_size,
                              hipStream_t stream) {
  const float* x      = (const float*)d_in[0];
  const float* temb   = (const float*)d_in[1];
  const float* nsc    = (const float*)d_in[2];
  const float* nbi    = (const float*)d_in[3];
  const float* qkv_w  = (const float*)d_in[4];
  const float* qkv_b  = (const float*)d_in[5];
  const float* proj_w = (const float*)d_in[6];
  const float* proj_b = (const float*)d_in[7];
  const float* dw     = (const float*)d_in[8];
  const float* db     = (const float*)d_in[9];
  const float* tw     = (const float*)d_in[10];
  const float* tb     = (const float*)d_in[11];
  const float* ow     = (const float*)d_in[12];
  const float* ob     = (const float*)d_in[13];
  const int*   fidx   = (const int*)d_in[14];
  float* out = (float*)d_out;
  u16* pun = (u16*)d_out;                        // slot-packed O (lo) + xn (hi)

  float* twT = (float*)d_ws;                     // 786432 f
  u16* wpk2 = (u16*)(twT + 786432);              // 196608 u16
  u16* ppk  = wpk2 + 196608;                     // 65536
  u16* opk  = ppk + 65536;                       // 196608
  u16* E    = opk + 196608;                      // 1572864
  u16* Rq   = E + 1572864;                       // 524288
  u16* Rk   = Rq + 524288;                       // 524288
  u16* Rv   = Rk + 524288;                       // 524288  (~10.4 MB total)

  k_prep<<<992, 256, 0, stream>>>(qkv_w, proj_w, ow, tw, wpk2, ppk, opk, twT);
  k_tpe<<<192, 256, 0, stream>>>(temb, twT, tb, dw, db, fidx, E);
  k_rgemm<<<192, 256, 0, stream>>>(E, opk, ob, Rq, Rk, Rv);
  k_gn<<<2048, 256, 0, stream>>>(x, nsc, nbi, pun);
  k_attn<<<16384, 256, 0, stream>>>(pun, wpk2, qkv_b, Rq, Rk, Rv);
  k_proj<<<2048, 256, 0, stream>>>(pun, ppk, proj_b, out);
}

// Round 6
// 434.636 us; speedup vs baseline: 5.3859x; 1.0092x over previous
//
#include <hip/hip_runtime.h>

#define BB 2
#define DD 1024
#define CC 256
#define TT 32
#define HH 8
#define FF 32
#define EE 1024
#define SCALE 0.17677669529663687f

typedef unsigned short u16;
typedef unsigned int u32;
typedef __attribute__((ext_vector_type(8))) short s8v;    // 8 bf16 (4 VGPRs)
typedef __attribute__((ext_vector_type(4))) float f32x4;

static __device__ __forceinline__ float u2f(u16 u) {
  return __uint_as_float(((u32)u) << 16);
}
static __device__ __forceinline__ u16 f2u(float f) {
  u32 x = __float_as_uint(f);
  x += 0x7fffu + ((x >> 16) & 1u);   // round-to-nearest-even
  return (u16)(x >> 16);
}
// acc += a.lo*b.lo + a.hi*b.hi  (bf16 pairs, f32 accumulate)
static __device__ __forceinline__ float dot2bf(u32 a, u32 b, float c) {
  float d;
  asm("v_dot2_f32_bf16 %0, %1, %2, %3" : "=v"(d) : "v"(a), "v"(b), "v"(c));
  return d;
}
#define D2(acc, a, b) acc = dot2bf(a, b, acc)

// logits for one (t,s): q.(k+rk) + k.rqs   (rqs pre-scaled by SCALE)
static __device__ __forceinline__ float logits_row(
    const u16* kr,
    uint4 r0, uint4 r1, uint4 r2, uint4 r3,
    uint4 r4, uint4 r5, uint4 r6, uint4 r7,
    uint4 q0, uint4 q1, uint4 q2, uint4 q3) {
  uint4 k0 = *(const uint4*)(kr + 0);
  uint4 k1 = *(const uint4*)(kr + 8);
  uint4 k2 = *(const uint4*)(kr + 16);
  uint4 k3 = *(const uint4*)(kr + 24);
  float xq = 0.f, xr = 0.f, xk = 0.f;
  D2(xq, q0.x, k0.x); D2(xq, q0.y, k0.y); D2(xq, q0.z, k0.z); D2(xq, q0.w, k0.w);
  D2(xq, q1.x, k1.x); D2(xq, q1.y, k1.y); D2(xq, q1.z, k1.z); D2(xq, q1.w, k1.w);
  D2(xq, q2.x, k2.x); D2(xq, q2.y, k2.y); D2(xq, q2.z, k2.z); D2(xq, q2.w, k2.w);
  D2(xq, q3.x, k3.x); D2(xq, q3.y, k3.y); D2(xq, q3.z, k3.z); D2(xq, q3.w, k3.w);
  D2(xr, q0.x, r0.x); D2(xr, q0.y, r0.y); D2(xr, q0.z, r0.z); D2(xr, q0.w, r0.w);
  D2(xr, q1.x, r1.x); D2(xr, q1.y, r1.y); D2(xr, q1.z, r1.z); D2(xr, q1.w, r1.w);
  D2(xr, q2.x, r2.x); D2(xr, q2.y, r2.y); D2(xr, q2.z, r2.z); D2(xr, q2.w, r2.w);
  D2(xr, q3.x, r3.x); D2(xr, q3.y, r3.y); D2(xr, q3.z, r3.z); D2(xr, q3.w, r3.w);
  D2(xk, k0.x, r4.x); D2(xk, k0.y, r4.y); D2(xk, k0.z, r4.z); D2(xk, k0.w, r4.w);
  D2(xk, k1.x, r5.x); D2(xk, k1.y, r5.y); D2(xk, k1.z, r5.z); D2(xk, k1.w, r5.w);
  D2(xk, k2.x, r6.x); D2(xk, k2.y, r6.y); D2(xk, k2.z, r6.z); D2(xk, k2.w, r6.w);
  D2(xk, k3.x, r7.x); D2(xk, k3.y, r7.y); D2(xk, k3.z, r7.z); D2(xk, k3.w, r7.w);
  return xq + xr + xk;
}

static __device__ __forceinline__ float pv16(
    uint4 p0, uint4 p1, uint4 p2, uint4 p3,
    uint4 v0, uint4 v1, uint4 v2, uint4 v3) {
  float o = 0.f;
  D2(o, p0.x, v0.x); D2(o, p0.y, v0.y); D2(o, p0.z, v0.z); D2(o, p0.w, v0.w);
  D2(o, p1.x, v1.x); D2(o, p1.y, v1.y); D2(o, p1.z, v1.z); D2(o, p1.w, v1.w);
  D2(o, p2.x, v2.x); D2(o, p2.y, v2.y); D2(o, p2.z, v2.z); D2(o, p2.w, v2.w);
  D2(o, p3.x, v3.x); D2(o, p3.y, v3.y); D2(o, p3.z, v3.z); D2(o, p3.w, v3.w);
  return o;
}

// ---------------------------------------------------------------------------
// K0: pack weights into MFMA-fragment order (bf16) + transpose tw -> twT (f32)
__global__ void k_prep(const float* __restrict__ qw, const float* __restrict__ pw,
                       const float* __restrict__ ow, const float* __restrict__ tw,
                       u16* __restrict__ wpk2, u16* __restrict__ ppk,
                       u16* __restrict__ opk, float* __restrict__ twT) {
  int id = blockIdx.x * 256 + threadIdx.x;
  if (id < 24576) {
    int lane = id & 63, ks = (id >> 6) & 7, tile = id >> 9;   // 0..47
    int hh = tile / 6, r = tile % 6, sec = r >> 1, nt = r & 1;
    int nrow = sec * 256 + hh * 32 + nt * 16 + (lane & 15);
    int k = ks * 32 + (lane >> 4) * 8;
    const float* src = qw + (size_t)nrow * 256 + k;
    u16* dst = wpk2 + (size_t)id * 8;
#pragma unroll
    for (int e = 0; e < 8; ++e) dst[e] = f2u(src[e]);
  } else if (id < 32768) {
    int j = id - 24576;
    int lane = j & 63, ks = (j >> 6) & 7, nt = j >> 9;
    int row = nt * 16 + (lane & 15);
    int k = ks * 32 + (lane >> 4) * 8;
    const float* src = pw + (size_t)row * 256 + k;
    u16* dst = ppk + (size_t)j * 8;
#pragma unroll
    for (int e = 0; e < 8; ++e) dst[e] = f2u(src[e]);
  } else if (id < 57344) {
    int j = id - 32768;
    int lane = j & 63, ks = (j >> 6) & 7, g = j >> 9;
    int n = g >> 4, ntg = g & 15;
    int row = ntg * 16 + (lane & 15);
    int k = ks * 32 + (lane >> 4) * 8;
    const float* src = ow + ((size_t)n * 256 + row) * 256 + k;
    u16* dst = opk + (size_t)j * 8;
#pragma unroll
    for (int e = 0; e < 8; ++e) dst[e] = f2u(src[e]);
  } else {
    int j = id - 57344;                 // 0..196607
    int n = j >> 16, r = j & 65535;
    int e = r >> 6, c0 = (r & 63) * 4;
    float4 v;
    v.x = tw[((size_t)n * 256 + c0 + 0) * 1024 + e];
    v.y = tw[((size_t)n * 256 + c0 + 1) * 1024 + e];
    v.z = tw[((size_t)n * 256 + c0 + 2) * 1024 + e];
    v.w = tw[((size_t)n * 256 + c0 + 3) * 1024 + e];
    *(float4*)(twT + (size_t)n * 262144 + (size_t)e * 256 + c0) = v;
  }
}

// ---------------------------------------------------------------------------
// K1: per (n,b,t): temb-proj + dist/silu -> E bf16 rows [n*2048+b*1024+t*32+s][256]
__global__ __launch_bounds__(256) void k_tpe(
    const float* __restrict__ temb, const float* __restrict__ twT,
    const float* __restrict__ tb, const float* __restrict__ dw,
    const float* __restrict__ db, const int* __restrict__ fidx,
    u16* __restrict__ E) {
  int bid = blockIdx.x;           // n*64 + b*32 + t
  int t = bid & 31, b = (bid >> 5) & 1, n = bid >> 6;
  __shared__ float st[EE];
  __shared__ int sfi[TT];
  for (int e = threadIdx.x; e < EE; e += 256)
    st[e] = temb[((size_t)b * TT + t) * EE + e];
  if (threadIdx.x < TT) sfi[threadIdx.x] = fidx[b * TT + threadIdx.x];
  __syncthreads();
  int c = threadIdx.x;
  const float* wp = twT + (size_t)n * 262144 + c;
  float a0 = 0.f, a1 = 0.f, a2 = 0.f, a3 = 0.f;
  for (int e = 0; e < EE; e += 4) {
    a0 += st[e + 0] * wp[(size_t)(e + 0) * 256];
    a1 += st[e + 1] * wp[(size_t)(e + 1) * 256];
    a2 += st[e + 2] * wp[(size_t)(e + 2) * 256];
    a3 += st[e + 3] * wp[(size_t)(e + 3) * 256];
  }
  float base = a0 + a1 + a2 + a3 + tb[n * 256 + c] + db[n * 256 + c];
  float dw0 = dw[(n * 256 + c) * 3 + 0];
  float dw1 = dw[(n * 256 + c) * 3 + 1];
  float dw2 = dw[(n * 256 + c) * 3 + 2];
  int ft = sfi[t];
  u16* erow = E + ((size_t)n * 2048 + b * 1024 + t * 32) * 256 + c;
  for (int s = 0; s < TT; ++s) {
    int pd = ft - sfi[s];
    float d0 = log1pf((float)(pd > 0 ? pd : 0));
    float d1 = log1pf((float)(pd < 0 ? -pd : 0));
    float d2 = (pd == 0) ? 1.f : 0.f;
    float e = base + d0 * dw0 + d1 * dw1 + d2 * dw2;
    float se = e / (1.f + expf(-e));
    erow[(size_t)s * 256] = f2u(se);
  }
}

// ---------------------------------------------------------------------------
// K2: R = E @ ow^T + ob via MFMA, stored head-major:
//  n=0 (Rq, pre-scaled by SCALE, (t,s)-swapped) -> RKQ[bh][t*32+s][32+f]
//  n=1 (Rk)                                     -> RKQ[bh][t*32+s][f]
//  n=2 (Rv)                                     -> Rv [bh][t][f][s]
__global__ __launch_bounds__(256) void k_rgemm(
    const u16* __restrict__ E, const u16* __restrict__ opk,
    const float* __restrict__ ob,
    u16* __restrict__ RKQ, u16* __restrict__ Rv) {
  int bid = blockIdx.x;                 // 192 = 3n * 32 mblk * 2 nblk
  int n = bid >> 6, rem = bid & 63;
  int mblk = rem >> 1, nblk = rem & 1;
  int tid = threadIdx.x;
  int w = tid >> 6, lane = tid & 63;
  int l15 = lane & 15, l4 = lane >> 4;
  size_t rowbase = (size_t)n * 2048 + mblk * 64;

  f32x4 acc[2][4];
#pragma unroll
  for (int i = 0; i < 2; ++i) {
    int ntg = nblk * 8 + w * 2 + i;
    float ov = ob[n * 256 + ntg * 16 + l15];
#pragma unroll
    for (int mt = 0; mt < 4; ++mt) acc[i][mt] = (f32x4){ov, ov, ov, ov};
  }
  for (int ks = 0; ks < 8; ++ks) {
    s8v a[4];
#pragma unroll
    for (int mt = 0; mt < 4; ++mt)
      a[mt] = *(const s8v*)(E + (rowbase + mt * 16 + l15) * 256 + ks * 32 + l4 * 8);
#pragma unroll
    for (int i = 0; i < 2; ++i) {
      int ntg = nblk * 8 + w * 2 + i;
      s8v bf = *(const s8v*)(opk + (((size_t)(n * 16 + ntg) * 8 + ks) * 64 + lane) * 8);
#pragma unroll
      for (int mt = 0; mt < 4; ++mt)
        acc[i][mt] = __builtin_amdgcn_mfma_f32_16x16x32_bf16(a[mt], bf, acc[i][mt], 0, 0, 0);
    }
  }
#pragma unroll
  for (int i = 0; i < 2; ++i) {
    int cc = (nblk * 8 + w * 2 + i) * 16 + l15;
    int hh = cc >> 5, f = cc & 31;
#pragma unroll
    for (int mt = 0; mt < 4; ++mt)
#pragma unroll
      for (int r = 0; r < 4; ++r) {
        int rloc = mblk * 64 + mt * 16 + l4 * 4 + r;  // 0..2047
        int bb2 = rloc >> 10, tt = (rloc >> 5) & 31, ss = rloc & 31;
        size_t bh = (size_t)(bb2 * 8 + hh);
        float v = acc[i][mt][r];
        if (n == 0)      RKQ[(bh * 1024 + ss * 32 + tt) * 64 + 32 + f] = f2u(v * SCALE);
        else if (n == 1) RKQ[(bh * 1024 + tt * 32 + ss) * 64 + f] = f2u(v);
        else             Rv[((bh * 32 + tt) * 32 + f) * 32 + ss] = f2u(v);
      }
  }
}

// ---------------------------------------------------------------------------
// K3: groupnorm -> xn bf16, stored in upper half of this (b,d)'s d_out slot
__global__ __launch_bounds__(256, 4) void k_gn(
    const float* __restrict__ x, const float* __restrict__ nsc,
    const float* __restrict__ nbi, u16* __restrict__ pun) {
  int bid = blockIdx.x;
  int xcd = bid & 7, jj = bid >> 3;
  int b = xcd >> 2;
  int d = (xcd & 3) * 256 + jj;
  const int tid = threadIdx.x;
  __shared__ u16 xt[TT][264];
  const size_t xbase = ((size_t)(b * DD + d)) * 8192;
  u16* xnp = pun + xbase * 2 + 8192;     // upper half of the 32KB slot
  {
    const int c0 = tid >> 3, tq = tid & 7;
    for (int c = c0; c < CC; c += 32) {
      float4 v = *(const float4*)(x + xbase + (size_t)c * TT + tq * 4);
      xt[tq * 4 + 0][c] = f2u(v.x);
      xt[tq * 4 + 1][c] = f2u(v.y);
      xt[tq * 4 + 2][c] = f2u(v.z);
      xt[tq * 4 + 3][c] = f2u(v.w);
    }
  }
  __syncthreads();
  {
    const int c = tid;
    float s = 0.f, s2 = 0.f;
    for (int t = 0; t < TT; ++t) { float v = u2f(xt[t][c]); s += v; s2 += v * v; }
    s += __shfl_xor(s, 1); s2 += __shfl_xor(s2, 1);
    s += __shfl_xor(s, 2); s2 += __shfl_xor(s2, 2);
    s += __shfl_xor(s, 4); s2 += __shfl_xor(s2, 4);
    const float mean = s * (1.f / 256.f);
    const float var = s2 * (1.f / 256.f) - mean * mean;
    const float rs = rsqrtf(var + 1e-5f);
    const float scv = nsc[c] * rs;
    const float biv = nbi[c] - mean * scv;
    for (int t = 0; t < TT; ++t) xt[t][c] = f2u(u2f(xt[t][c]) * scv + biv);
  }
  __syncthreads();
#pragma unroll
  for (int it = 0; it < 4; ++it) {       // 1024 ushort8 units = 32x256
    int u = it * 256 + tid;
    int t = u >> 5, c = (u & 31) * 8;
    *(uint4*)(xnp + (size_t)u * 8) = *(const uint4*)&xt[t][c];
  }
}

// ---------------------------------------------------------------------------
// K4: per (b,d,h): qkv MFMA -> logits/softmax/PV, all reg tiles NAMED,
// R gathers software-pipelined (m0/m1 pre-issued under MFMA phase).
__global__ __launch_bounds__(256, 4) void k_attn(
    u16* __restrict__ pun, const u16* __restrict__ wpk2,
    const float* __restrict__ qkb,
    const u16* __restrict__ RKQ, const u16* __restrict__ Rv) {
  int bid = blockIdx.x;
  int xcd = bid & 7, jj = bid >> 3;     // jj 0..2047
  int b = xcd >> 2;
  int h = jj & 7;                       // h fastest: same-(b,d) blocks share an XCD
  int d = (xcd & 3) * 256 + (jj >> 3);
  const int tid = threadIdx.x;
  __shared__ u16 xs[32][264];
  __shared__ u16 qs[32][40];
  __shared__ u16 ks_[32][40];
  __shared__ u16 vT[32][40];    // v transposed: [f][s]
  __shared__ u16 ats[32][40];   // softmax'd attn, bf16

  u16* slot = pun + ((size_t)(b * DD + d)) * 16384;   // O half, +8192 = xn half
  const int t = tid >> 3, j = tid & 7;
  const size_t bh = (size_t)(b * 8 + h);

  // ---- issue xn staging loads
  uint4 x0 = *(const uint4*)(slot + 8192 + (size_t)(tid) * 8);
  uint4 x1 = *(const uint4*)(slot + 8192 + (size_t)(256 + tid) * 8);
  uint4 x2 = *(const uint4*)(slot + 8192 + (size_t)(512 + tid) * 8);
  uint4 x3 = *(const uint4*)(slot + 8192 + (size_t)(768 + tid) * 8);

  // ---- pre-issue R rows for m0, m1 (hidden under MFMA phase)
  const u16* rp0 = RKQ + (bh * 1024 + (size_t)t * 32 + j) * 64;
  const u16* rp1 = rp0 + 8 * 64;
  uint4 A0 = *(const uint4*)(rp0 + 0),  A1 = *(const uint4*)(rp0 + 8);
  uint4 A2 = *(const uint4*)(rp0 + 16), A3 = *(const uint4*)(rp0 + 24);
  uint4 A4 = *(const uint4*)(rp0 + 32), A5 = *(const uint4*)(rp0 + 40);
  uint4 A6 = *(const uint4*)(rp0 + 48), A7 = *(const uint4*)(rp0 + 56);
  uint4 B0 = *(const uint4*)(rp1 + 0),  B1 = *(const uint4*)(rp1 + 8);
  uint4 B2 = *(const uint4*)(rp1 + 16), B3 = *(const uint4*)(rp1 + 24);
  uint4 B4 = *(const uint4*)(rp1 + 32), B5 = *(const uint4*)(rp1 + 40);
  uint4 B6 = *(const uint4*)(rp1 + 48), B7 = *(const uint4*)(rp1 + 56);

  // ---- write xs
  {
    int u0 = tid, u1 = 256 + tid, u2 = 512 + tid, u3 = 768 + tid;
    *(uint4*)&xs[u0 >> 5][(u0 & 31) * 8] = x0;
    *(uint4*)&xs[u1 >> 5][(u1 & 31) * 8] = x1;
    *(uint4*)&xs[u2 >> 5][(u2 & 31) * 8] = x2;
    *(uint4*)&xs[u3 >> 5][(u3 & 31) * 8] = x3;
  }
  __syncthreads();

  // ---- qkv head-slice MFMA (waves 0..2 = q,k,v)
  const int w = tid >> 6, lane = tid & 63;
  const int l15 = lane & 15, l4 = lane >> 4;
  if (w < 3) {
    f32x4 acc00 = {0.f, 0.f, 0.f, 0.f}, acc01 = acc00;
    f32x4 acc10 = acc00, acc11 = acc00;
    for (int ks = 0; ks < 8; ++ks) {
      s8v a0 = *(const s8v*)&xs[l15][ks * 32 + l4 * 8];
      s8v a1 = *(const s8v*)&xs[16 + l15][ks * 32 + l4 * 8];
      s8v bf0 = *(const s8v*)(wpk2 + ((size_t)((h * 6 + w * 2 + 0) * 8 + ks) * 64 + lane) * 8);
      s8v bf1 = *(const s8v*)(wpk2 + ((size_t)((h * 6 + w * 2 + 1) * 8 + ks) * 64 + lane) * 8);
      acc00 = __builtin_amdgcn_mfma_f32_16x16x32_bf16(a0, bf0, acc00, 0, 0, 0);
      acc01 = __builtin_amdgcn_mfma_f32_16x16x32_bf16(a1, bf0, acc01, 0, 0, 0);
      acc10 = __builtin_amdgcn_mfma_f32_16x16x32_bf16(a0, bf1, acc10, 0, 0, 0);
      acc11 = __builtin_amdgcn_mfma_f32_16x16x32_bf16(a1, bf1, acc11, 0, 0, 0);
    }
#pragma unroll
    for (int nt = 0; nt < 2; ++nt) {
      int f = nt * 16 + l15;
      float bias = qkb[w * 256 + h * 32 + f];
#pragma unroll
      for (int mt = 0; mt < 2; ++mt) {
        f32x4 av = (nt == 0) ? (mt == 0 ? acc00 : acc01) : (mt == 0 ? acc10 : acc11);
#pragma unroll
        for (int r = 0; r < 4; ++r) {
          int tt = mt * 16 + l4 * 4 + r;
          float val = av[r] + bias;
          if (w == 0)      qs[tt][f] = f2u(val * SCALE);
          else if (w == 1) ks_[tt][f] = f2u(val);
          else             vT[f][tt] = f2u(val);
        }
      }
    }
  }
  __syncthreads();

  // ---- logits (pipelined consumes/issues)
  uint4 q0 = *(const uint4*)&qs[t][0],  q1 = *(const uint4*)&qs[t][8];
  uint4 q2 = *(const uint4*)&qs[t][16], q3 = *(const uint4*)&qs[t][24];
  const u16* rp2 = rp0 + 16 * 64;
  const u16* rp3 = rp0 + 24 * 64;
  uint4 C0 = *(const uint4*)(rp2 + 0),  C1 = *(const uint4*)(rp2 + 8);
  uint4 C2 = *(const uint4*)(rp2 + 16), C3 = *(const uint4*)(rp2 + 24);
  uint4 C4 = *(const uint4*)(rp2 + 32), C5 = *(const uint4*)(rp2 + 40);
  uint4 C6 = *(const uint4*)(rp2 + 48), C7 = *(const uint4*)(rp2 + 56);
  float a0v = logits_row(&ks_[j][0], A0, A1, A2, A3, A4, A5, A6, A7, q0, q1, q2, q3);
  uint4 D0 = *(const uint4*)(rp3 + 0),  D1 = *(const uint4*)(rp3 + 8);
  uint4 D2v = *(const uint4*)(rp3 + 16), D3 = *(const uint4*)(rp3 + 24);
  uint4 D4 = *(const uint4*)(rp3 + 32), D5 = *(const uint4*)(rp3 + 40);
  uint4 D6 = *(const uint4*)(rp3 + 48), D7 = *(const uint4*)(rp3 + 56);
  float a1v = logits_row(&ks_[j + 8][0],  B0, B1, B2, B3, B4, B5, B6, B7, q0, q1, q2, q3);
  float a2v = logits_row(&ks_[j + 16][0], C0, C1, C2, C3, C4, C5, C6, C7, q0, q1, q2, q3);
  float a3v = logits_row(&ks_[j + 24][0], D0, D1, D2v, D3, D4, D5, D6, D7, q0, q1, q2, q3);

  // ---- issue Rv rows (f = j+8i), consumed after softmax + LDS-half of PV
  const u16* rv0 = Rv + ((bh * 32 + (size_t)t) * 32 + j) * 32;
  const u16* rv1 = rv0 + 8 * 32;
  const u16* rv2 = rv0 + 16 * 32;
  const u16* rv3 = rv0 + 24 * 32;
  uint4 V00 = *(const uint4*)(rv0 + 0),  V01 = *(const uint4*)(rv0 + 8);
  uint4 V02 = *(const uint4*)(rv0 + 16), V03 = *(const uint4*)(rv0 + 24);
  uint4 V10 = *(const uint4*)(rv1 + 0),  V11 = *(const uint4*)(rv1 + 8);
  uint4 V12 = *(const uint4*)(rv1 + 16), V13 = *(const uint4*)(rv1 + 24);
  uint4 V20 = *(const uint4*)(rv2 + 0),  V21 = *(const uint4*)(rv2 + 8);
  uint4 V22 = *(const uint4*)(rv2 + 16), V23 = *(const uint4*)(rv2 + 24);
  uint4 V30 = *(const uint4*)(rv3 + 0),  V31 = *(const uint4*)(rv3 + 8);
  uint4 V32 = *(const uint4*)(rv3 + 16), V33 = *(const uint4*)(rv3 + 24);

  // ---- softmax over 32 s (8-lane groups x 4 regs)
  float mx = fmaxf(fmaxf(a0v, a1v), fmaxf(a2v, a3v));
  mx = fmaxf(mx, __shfl_xor(mx, 1));
  mx = fmaxf(mx, __shfl_xor(mx, 2));
  mx = fmaxf(mx, __shfl_xor(mx, 4));
  float e0 = __expf(a0v - mx), e1 = __expf(a1v - mx);
  float e2 = __expf(a2v - mx), e3 = __expf(a3v - mx);
  float sum = e0 + e1 + e2 + e3;
  sum += __shfl_xor(sum, 1);
  sum += __shfl_xor(sum, 2);
  sum += __shfl_xor(sum, 4);
  const float inv = 1.f / sum;
  ats[t][j]      = f2u(e0 * inv);
  ats[t][j + 8]  = f2u(e1 * inv);
  ats[t][j + 16] = f2u(e2 * inv);
  ats[t][j + 24] = f2u(e3 * inv);
  // (row t written & read by same 8-lane group of one wave -> no barrier)

  uint4 p0 = *(const uint4*)&ats[t][0],  p1 = *(const uint4*)&ats[t][8];
  uint4 p2 = *(const uint4*)&ats[t][16], p3 = *(const uint4*)&ats[t][24];

  // ---- PV LDS half (v), then Rv half
  uint4 w00 = *(const uint4*)&vT[j][0],       w01 = *(const uint4*)&vT[j][8];
  uint4 w02 = *(const uint4*)&vT[j][16],      w03 = *(const uint4*)&vT[j][24];
  float o0 = pv16(p0, p1, p2, p3, w00, w01, w02, w03);
  uint4 w10 = *(const uint4*)&vT[j + 8][0],   w11 = *(const uint4*)&vT[j + 8][8];
  uint4 w12 = *(const uint4*)&vT[j + 8][16],  w13 = *(const uint4*)&vT[j + 8][24];
  float o1 = pv16(p0, p1, p2, p3, w10, w11, w12, w13);
  uint4 w20 = *(const uint4*)&vT[j + 16][0],  w21 = *(const uint4*)&vT[j + 16][8];
  uint4 w22 = *(const uint4*)&vT[j + 16][16], w23 = *(const uint4*)&vT[j + 16][24];
  float o2 = pv16(p0, p1, p2, p3, w20, w21, w22, w23);
  uint4 w30 = *(const uint4*)&vT[j + 24][0],  w31 = *(const uint4*)&vT[j + 24][8];
  uint4 w32 = *(const uint4*)&vT[j + 24][16], w33 = *(const uint4*)&vT[j + 24][24];
  float o3 = pv16(p0, p1, p2, p3, w30, w31, w32, w33);
  o0 += pv16(p0, p1, p2, p3, V00, V01, V02, V03);
  o1 += pv16(p0, p1, p2, p3, V10, V11, V12, V13);
  o2 += pv16(p0, p1, p2, p3, V20, V21, V22, V23);
  o3 += pv16(p0, p1, p2, p3, V30, V31, V32, V33);

  u16* op = slot + (size_t)t * 256 + h * 32 + j;
  op[0]  = f2u(o0);
  op[8]  = f2u(o1);
  op[16] = f2u(o2);
  op[24] = f2u(o3);
}

// ---------------------------------------------------------------------------
// K5: per (b,d): proj MFMA + bias + residual(xn) -> out [b][d][c][t] f32
__global__ __launch_bounds__(256, 4) void k_proj(
    u16* __restrict__ pun, const u16* __restrict__ ppk,
    const float* __restrict__ pb, float* __restrict__ out) {
  int bid = blockIdx.x;
  int xcd = bid & 7, jj = bid >> 3;
  int b = xcd >> 2;
  int d = (xcd & 3) * 256 + jj;
  const int tid = threadIdx.x;
  __shared__ u16 obuf[32][264];
  __shared__ u16 xs[32][264];
  const size_t nbase = ((size_t)(b * DD + d)) * 8192;
  u16* slot = pun + nbase * 2;
#pragma unroll
  for (int it = 0; it < 4; ++it) {
    int u = it * 256 + tid;
    int t = u >> 5, c = (u & 31) * 8;
    *(uint4*)&obuf[t][c] = *(const uint4*)(slot + (size_t)u * 8);
    *(uint4*)&xs[t][c]   = *(const uint4*)(slot + 8192 + (size_t)u * 8);
  }
  __syncthreads();

  const int w = tid >> 6, lane = tid & 63;
  const int l15 = lane & 15, l4 = lane >> 4;
  f32x4 pacc[4][2];
#pragma unroll
  for (int i = 0; i < 4; ++i) {
    pacc[i][0] = (f32x4){0.f, 0.f, 0.f, 0.f};
    pacc[i][1] = (f32x4){0.f, 0.f, 0.f, 0.f};
  }
  for (int ks = 0; ks < 8; ++ks) {
    s8v a0 = *(const s8v*)&obuf[l15][ks * 32 + l4 * 8];
    s8v a1 = *(const s8v*)&obuf[16 + l15][ks * 32 + l4 * 8];
#pragma unroll
    for (int i = 0; i < 4; ++i) {
      s8v bf = *(const s8v*)(ppk + ((size_t)((w * 4 + i) * 8 + ks) * 64 + lane) * 8);
      pacc[i][0] = __builtin_amdgcn_mfma_f32_16x16x32_bf16(a0, bf, pacc[i][0], 0, 0, 0);
      pacc[i][1] = __builtin_amdgcn_mfma_f32_16x16x32_bf16(a1, bf, pacc[i][1], 0, 0, 0);
    }
  }
#pragma unroll
  for (int i = 0; i < 4; ++i) {
    const int co = (w * 4 + i) * 16 + l15;
    const float pbv = pb[co];
#pragma unroll
    for (int mt = 0; mt < 2; ++mt) {
      const int t0 = mt * 16 + l4 * 4;
      float4 sv;
      sv.x = pacc[i][mt][0] + u2f(xs[t0 + 0][co]) + pbv;
      sv.y = pacc[i][mt][1] + u2f(xs[t0 + 1][co]) + pbv;
      sv.z = pacc[i][mt][2] + u2f(xs[t0 + 2][co]) + pbv;
      sv.w = pacc[i][mt][3] + u2f(xs[t0 + 3][co]) + pbv;
      *(float4*)(out + nbase + (size_t)co * TT + t0) = sv;
    }
  }
}

// ---------------------------------------------------------------------------
extern "C" void kernel_launch(void* const* d_in, const int* in_sizes, int n_in,
                              void* d_out, int out_size, void* d_ws, size_t ws_size,
                              hipStream_t stream) {
  const float* x      = (const float*)d_in[0];
  const float* temb   = (const float*)d_in[1];
  const float* nsc    = (const float*)d_in[2];
  const float* nbi    = (const float*)d_in[3];
  const float* qkv_w  = (const float*)d_in[4];
  const float* qkv_b  = (const float*)d_in[5];
  const float* proj_w = (const float*)d_in[6];
  const float* proj_b = (const float*)d_in[7];
  const float* dw     = (const float*)d_in[8];
  const float* db     = (const float*)d_in[9];
  const float* tw     = (const float*)d_in[10];
  const float* tb     = (const float*)d_in[11];
  const float* ow     = (const float*)d_in[12];
  const float* ob     = (const float*)d_in[13];
  const int*   fidx   = (const int*)d_in[14];
  float* out = (float*)d_out;
  u16* pun = (u16*)d_out;                        // slot-packed O (lo) + xn (hi)

  float* twT = (float*)d_ws;                     // 786432 f
  u16* wpk2 = (u16*)(twT + 786432);              // 196608 u16
  u16* ppk  = wpk2 + 196608;                     // 65536
  u16* opk  = ppk + 65536;                       // 196608
  u16* E    = opk + 196608;                      // 1572864
  u16* RKQ  = E + 1572864;                       // 16*1024*64 = 1048576
  u16* Rv   = RKQ + 1048576;                     // 524288   (~10.3 MB total)

  k_prep<<<992, 256, 0, stream>>>(qkv_w, proj_w, ow, tw, wpk2, ppk, opk, twT);
  k_tpe<<<192, 256, 0, stream>>>(temb, twT, tb, dw, db, fidx, E);
  k_rgemm<<<192, 256, 0, stream>>>(E, opk, ob, RKQ, Rv);
  k_gn<<<2048, 256, 0, stream>>>(x, nsc, nbi, pun);
  k_attn<<<16384, 256, 0, stream>>>(pun, wpk2, qkv_b, RKQ, Rv);
  k_proj<<<2048, 256, 0, stream>>>(pun, ppk, proj_b, out);
}